// Round 20
// baseline (20195.639 us; speedup 1.0000x reference)
//
#include <hip/hip_runtime.h>
#include <math.h>

#define B_ 32
#define N_ 1024
#define C_ 512
#define H_ 256
#define V_ 50
#define T_ 501
#define CV_ 562     // C + V
#define G3_ 768     // 3*H
#define CHUNKS_ 32  // K1 blocks per batch row
#define POSB_ 32    // positions per K1 block

typedef float    f32x4 __attribute__((ext_vector_type(4)));
typedef _Float16 f16x4 __attribute__((ext_vector_type(4)));
typedef _Float16 f16x8 __attribute__((ext_vector_type(8)));

__device__ __forceinline__ float fast_rcp(float x) { return __builtin_amdgcn_rcpf(x); }
__device__ __forceinline__ float fast_tanh(float x) {
  float e = __expf(2.0f * x);
  return 1.0f - 2.0f * fast_rcp(e + 1.0f);
}
__device__ __forceinline__ float fast_sigmoid(float x) {
  return fast_rcp(1.0f + __expf(-x));
}
__device__ __forceinline__ void astore(float* p, float v) {
  __hip_atomic_store(p, v, __ATOMIC_RELAXED, __HIP_MEMORY_SCOPE_AGENT);
}
__device__ __forceinline__ float aload(const float* p) {
  return __hip_atomic_load(p, __ATOMIC_RELAXED, __HIP_MEMORY_SCOPE_AGENT);
}
__device__ __forceinline__ int aloadi(const int* p) {
  return __hip_atomic_load(p, __ATOMIC_RELAXED, __HIP_MEMORY_SCOPE_AGENT);
}

// ---------------- feat_proj GEMM: FPh[m][h] = fp16( sum_c A[m][c] * W[h][c] ) ----------------
__global__ __launch_bounds__(256) void fp_gemm(const float* __restrict__ A,
                                               const float* __restrict__ W,
                                               _Float16* __restrict__ FPh) {
  __shared__ __align__(16) float As[16][68];
  __shared__ __align__(16) float Ws[16][68];
  const int t = threadIdx.x;
  const int m0 = blockIdx.x * 64;
  const int h0 = blockIdx.y * 64;
  const int lr = t & 63;
  const int kg = t >> 6;
  const int tx = t & 15, ty = t >> 4;
  float acc[4][4] = {};
  for (int k0 = 0; k0 < C_; k0 += 16) {
    float4 av = *(const float4*)&A[(size_t)(m0 + lr) * C_ + k0 + kg * 4];
    float4 wv = *(const float4*)&W[(size_t)(h0 + lr) * C_ + k0 + kg * 4];
    As[kg*4+0][lr] = av.x; As[kg*4+1][lr] = av.y; As[kg*4+2][lr] = av.z; As[kg*4+3][lr] = av.w;
    Ws[kg*4+0][lr] = wv.x; Ws[kg*4+1][lr] = wv.y; Ws[kg*4+2][lr] = wv.z; Ws[kg*4+3][lr] = wv.w;
    __syncthreads();
#pragma unroll
    for (int kk = 0; kk < 16; ++kk) {
      float4 a = *(const float4*)&As[kk][ty * 4];
      float4 w = *(const float4*)&Ws[kk][tx * 4];
      acc[0][0] += a.x*w.x; acc[0][1] += a.x*w.y; acc[0][2] += a.x*w.z; acc[0][3] += a.x*w.w;
      acc[1][0] += a.y*w.x; acc[1][1] += a.y*w.y; acc[1][2] += a.y*w.z; acc[1][3] += a.y*w.w;
      acc[2][0] += a.z*w.x; acc[2][1] += a.z*w.y; acc[2][2] += a.z*w.z; acc[2][3] += a.z*w.w;
      acc[3][0] += a.w*w.x; acc[3][1] += a.w*w.y; acc[3][2] += a.w*w.z; acc[3][3] += a.w*w.w;
    }
    __syncthreads();
  }
#pragma unroll
  for (int i = 0; i < 4; ++i) {
    f16x4 o;
    o.x = (_Float16)acc[i][0]; o.y = (_Float16)acc[i][1];
    o.z = (_Float16)acc[i][2]; o.w = (_Float16)acc[i][3];
    *(f16x4*)&FPh[(size_t)(m0 + ty*4 + i) * H_ + h0 + tx*4] = o;
  }
}

// ---------------- feat -> fp16 (one-time) ----------------
__global__ void feat_to_fp16(const float* __restrict__ src, _Float16* __restrict__ dst,
                             int total4) {
  int i = blockIdx.x * 256 + threadIdx.x;
  if (i >= total4) return;
  f32x4 v = *(const f32x4*)&src[(size_t)i * 4];
  f16x4 o; o.x = (_Float16)v.x; o.y = (_Float16)v.y; o.z = (_Float16)v.z; o.w = (_Float16)v.w;
  *(f16x4*)&dst[(size_t)i * 4] = o;
}

// ---------------- weight transpose (one-time): dstA[c][j] = src[j][c] for c<splitc, rest -> dstB ----------------
__global__ void transpose_split(const float* __restrict__ src, float* __restrict__ dstA,
                                float* __restrict__ dstB, int rows, int cols, int splitc) {
  int i = blockIdx.x * 256 + threadIdx.x;
  if (i >= rows * cols) return;
  int j = i / cols, c = i - j * cols;
  float v = src[i];
  if (c < splitc) dstA[(size_t)c * rows + j] = v;
  else            dstB[(size_t)(c - splitc) * rows + j] = v;
}

// ---------------- init: h=0, pp=b_h2h, pre=0, cnt=0 ----------------
__global__ void init_kernel(const float* __restrict__ b_h2h, float* __restrict__ h,
                            float* __restrict__ pp, int* __restrict__ pre,
                            int* __restrict__ cnt) {
  int i = blockIdx.x * blockDim.x + threadIdx.x;
  if (i < B_ * H_) { h[i] = 0.0f; pp[i] = b_h2h[i & (H_ - 1)]; }
  if (i < B_) pre[i] = 0;
  if (i < T_ * 16) cnt[i] = 0;
}

// ---------------- K1: CHAMPION (R15) — untouched ----------------
__global__ __launch_bounds__(256) void k1_attn(
    const _Float16* __restrict__ feath, const _Float16* __restrict__ fph,
    const float* __restrict__ w_score, const float* __restrict__ pp,
    float* __restrict__ part_ctx, float* __restrict__ part_l) {
  __shared__ __align__(16) float lds_ctx[4 * C_];
  __shared__ float lds_l[4];

  const int t = threadIdx.x;
  const int wv = t >> 6;
  const int lane = t & 63;
  const int b = blockIdx.x >> 5;        // / CHUNKS_
  const int chunk = blockIdx.x & (CHUNKS_ - 1);

  float4 ppr = *(const float4*)&pp[b * H_ + lane * 4];
  float4 wsr = *(const float4*)&w_score[lane * 4];
  const int n0 = chunk * POSB_ + wv * 8;
  const _Float16* fp0 = fph + (size_t)b * N_ * H_ + (size_t)n0 * H_ + lane * 4;
  const _Float16* ft0 = feath + (size_t)b * N_ * C_ + (size_t)n0 * C_ + lane * 8;

  f16x4 v[8];
  f16x8 f[8];
#pragma unroll
  for (int i = 0; i < 8; ++i) {
    v[i] = __builtin_nontemporal_load((const f16x4*)(fp0 + (size_t)i * H_));
    f[i] = __builtin_nontemporal_load((const f16x8*)(ft0 + (size_t)i * C_));
  }

  float aA0 = 0.f, aA1 = 0.f, aA2 = 0.f, aA3 = 0.f;
  float aB0 = 0.f, aB1 = 0.f, aB2 = 0.f, aB3 = 0.f;
  float lacc = 0.f;
#pragma unroll
  for (int i = 0; i < 8; ++i) {
    float s = fast_tanh((float)v[i].x + ppr.x) * wsr.x + fast_tanh((float)v[i].y + ppr.y) * wsr.y
            + fast_tanh((float)v[i].z + ppr.z) * wsr.z + fast_tanh((float)v[i].w + ppr.w) * wsr.w;
#pragma unroll
    for (int off = 32; off > 0; off >>= 1) s += __shfl_xor(s, off);
    float p = __expf(s);   // |s| <= sum|w_score| ~ 10 -> safe without max-subtraction
    lacc += p;
    aA0 += p * (float)f[i].s0; aA1 += p * (float)f[i].s1; aA2 += p * (float)f[i].s2; aA3 += p * (float)f[i].s3;
    aB0 += p * (float)f[i].s4; aB1 += p * (float)f[i].s5; aB2 += p * (float)f[i].s6; aB3 += p * (float)f[i].s7;
  }
  {
    float4 o0; o0.x = aA0; o0.y = aA1; o0.z = aA2; o0.w = aA3;
    float4 o1; o1.x = aB0; o1.y = aB1; o1.z = aB2; o1.w = aB3;
    *(float4*)&lds_ctx[wv * C_ + lane * 8] = o0;
    *(float4*)&lds_ctx[wv * C_ + lane * 8 + 4] = o1;
  }
  if (lane == 0) lds_l[wv] = lacc;
  __syncthreads();
  {
    float c0 = lds_ctx[t] + lds_ctx[C_ + t] + lds_ctx[2 * C_ + t] + lds_ctx[3 * C_ + t];
    float c1 = lds_ctx[t + 256] + lds_ctx[C_ + t + 256] + lds_ctx[2 * C_ + t + 256] + lds_ctx[3 * C_ + t + 256];
    float* pc = &part_ctx[((size_t)b * CHUNKS_ + chunk) * C_];
    pc[t] = c0;
    pc[t + 256] = c1;
    if (t == 0) part_l[b * CHUNKS_ + chunk] = lds_l[0] + lds_l[1] + lds_l[2] + lds_l[3];
  }
}

// ---------------- ktail: kred + gates + per-b tail in ONE 48-block kernel ----------------
// Barriers via arrive-and-spin (48 blocks <= CU count -> co-resident). Cross-XCD intermediates
// use device-scope astore/aload; cross-step state (h, pp) stays plain (kernel-boundary coherent).
__global__ __launch_bounds__(256) void ktail(
    int tstep,
    const float* __restrict__ part_ctx, const float* __restrict__ part_l,
    float* __restrict__ ctx_raw, float* __restrict__ l_total,
    float* __restrict__ h,
    const float* __restrict__ WtA, const float* __restrict__ WtH,
    float* __restrict__ pgi, float* __restrict__ pgh,
    const float* __restrict__ WtO,
    const float* __restrict__ b_gru_ih, const float* __restrict__ b_gru_hh,
    const float* __restrict__ Wt_s1, const float* __restrict__ b_s1,
    const float* __restrict__ Wt_h2h, const float* __restrict__ b_h2h,
    const float* __restrict__ w_s2, const float* __restrict__ b_s2,
    float* __restrict__ pp, int* __restrict__ pre,
    int* __restrict__ cnt, float* __restrict__ out) {
  __shared__ __align__(16) float smem[6144];   // B: wlds[4096]+clds[2048]; C: shn/ss1/sst
  const int blk = blockIdx.x;   // 0..47
  const int t = threadIdx.x;

  // ================= Phase A: ctx/l reduction (blocks 0..31) =================
  if (blk < B_) {
    const int b = blk;
    const float* src = part_ctx + (size_t)b * CHUNKS_ * C_;
    float s0 = 0.f, s1 = 0.f;
#pragma unroll 8
    for (int ch = 0; ch < CHUNKS_; ++ch) {
      s0 += src[(size_t)ch * C_ + t];
      s1 += src[(size_t)ch * C_ + t + 256];
    }
    astore(&ctx_raw[b * C_ + t], s0);
    astore(&ctx_raw[b * C_ + t + 256], s1);
    if (t < 64) {
      float lv = (t < CHUNKS_) ? part_l[b * CHUNKS_ + t] : 0.0f;
#pragma unroll
      for (int off = 32; off > 0; off >>= 1) lv += __shfl_xor(lv, off);
      if (t == 0) astore(&l_total[b], lv);
    }
  }
  // ---- barrier 1 ----
  asm volatile("s_waitcnt vmcnt(0)" ::: "memory");
  __syncthreads();
  if (t == 0) {
    atomicAdd(&cnt[tstep * 16], 1);
    while (aloadi(&cnt[tstep * 16]) < 48) __builtin_amdgcn_s_sleep(1);
  }
  __syncthreads();

  // ================= Phase B: gate GEMM (all 48 blocks) =================
  {
    const int jg = blk % 12, ks = blk / 12;
    const int j0 = jg * 64;
    const int jl = (t & 31) * 2;
    const int b0 = (t >> 5) * 4;
    float* wlds = smem;           // [64][64]
    float* clds = smem + 4096;    // [32][64]

    float acc[2][4] = {};
#pragma unroll
    for (int kt = 0; kt < 2; ++kt) {
      const int k0 = ks * 128 + kt * 64;
      __syncthreads();
#pragma unroll
      for (int q = 0; q < 4; ++q) {
        int idx = q * 256 + t; int r = idx >> 4, f4 = (idx & 15) * 4;
        *(float4*)&wlds[r * 64 + f4] = *(const float4*)&WtA[(size_t)(k0 + r) * G3_ + j0 + f4];
      }
#pragma unroll
      for (int q = 0; q < 8; ++q) {   // device-scope loads: ctx_raw written this kernel
        int idx = q * 256 + t; int bb = idx >> 6, k = idx & 63;
        clds[bb * 64 + k] = aload(&ctx_raw[bb * C_ + k0 + k]);
      }
      __syncthreads();
#pragma unroll 8
      for (int k = 0; k < 64; ++k) {
        float w0 = wlds[k * 64 + jl], w1 = wlds[k * 64 + jl + 1];
        float x0 = clds[b0 * 64 + k], x1 = clds[(b0 + 1) * 64 + k];
        float x2 = clds[(b0 + 2) * 64 + k], x3 = clds[(b0 + 3) * 64 + k];
        acc[0][0] += w0 * x0; acc[0][1] += w0 * x1; acc[0][2] += w0 * x2; acc[0][3] += w0 * x3;
        acc[1][0] += w1 * x0; acc[1][1] += w1 * x1; acc[1][2] += w1 * x2; acc[1][3] += w1 * x3;
      }
    }
#pragma unroll
    for (int i = 0; i < 2; ++i)
#pragma unroll
      for (int q = 0; q < 4; ++q)
        astore(&pgi[((size_t)ks * B_ + b0 + q) * G3_ + j0 + jl + i], acc[i][q]);

    float acb[2][4] = {};
    {
      const int k0 = ks * 64;
      __syncthreads();
#pragma unroll
      for (int q = 0; q < 4; ++q) {
        int idx = q * 256 + t; int r = idx >> 4, f4 = (idx & 15) * 4;
        *(float4*)&wlds[r * 64 + f4] = *(const float4*)&WtH[(size_t)(k0 + r) * G3_ + j0 + f4];
      }
#pragma unroll
      for (int q = 0; q < 2; ++q) {   // h from previous step's launch: plain loads coherent
        int idx = q * 256 + t; int bb = idx >> 4, f4 = (idx & 15) * 4;
        *(float4*)&clds[bb * 64 + f4] = *(const float4*)&h[(size_t)bb * H_ + k0 + f4];
      }
      __syncthreads();
#pragma unroll 8
      for (int k = 0; k < 64; ++k) {
        float w0 = wlds[k * 64 + jl], w1 = wlds[k * 64 + jl + 1];
        float x0 = clds[b0 * 64 + k], x1 = clds[(b0 + 1) * 64 + k];
        float x2 = clds[(b0 + 2) * 64 + k], x3 = clds[(b0 + 3) * 64 + k];
        acb[0][0] += w0 * x0; acb[0][1] += w0 * x1; acb[0][2] += w0 * x2; acb[0][3] += w0 * x3;
        acb[1][0] += w1 * x0; acb[1][1] += w1 * x1; acb[1][2] += w1 * x2; acb[1][3] += w1 * x3;
      }
    }
#pragma unroll
    for (int i = 0; i < 2; ++i)
#pragma unroll
      for (int q = 0; q < 4; ++q)
        astore(&pgh[((size_t)ks * B_ + b0 + q) * G3_ + j0 + jl + i], acb[i][q]);
  }
  // ---- barrier 2 (blocks 32..47 arrive and exit) ----
  asm volatile("s_waitcnt vmcnt(0)" ::: "memory");
  __syncthreads();
  if (t == 0) atomicAdd(&cnt[tstep * 16 + 8], 1);
  if (blk >= B_) return;
  if (t == 0) {
    while (aloadi(&cnt[tstep * 16 + 8]) < 48) __builtin_amdgcn_s_sleep(1);
  }
  __syncthreads();

  // ================= Phase C: per-b tail (blocks 0..31, 256 threads) =================
  {
    const int b = blk;
    float* shn = smem;          // [256]
    float* ss1 = smem + 256;    // [256]
    float* sst = smem + 512;    // [64]
    const int prev = pre[b];
    const float invl = 1.0f / aload(&l_total[b]);
    float gi0 = 0.f, gi1 = 0.f, gi2 = 0.f, gh0 = 0.f, gh1 = 0.f, gh2 = 0.f;
#pragma unroll
    for (int ks = 0; ks < 4; ++ks) {
      const float* pg = pgi + ((size_t)ks * B_ + b) * G3_;
      const float* ph = pgh + ((size_t)ks * B_ + b) * G3_;
      gi0 += aload(&pg[t]); gi1 += aload(&pg[t + 256]); gi2 += aload(&pg[t + 512]);
      gh0 += aload(&ph[t]); gh1 += aload(&ph[t + 256]); gh2 += aload(&ph[t + 512]);
    }
    const float* wo = WtO + (size_t)prev * G3_;
    gi0 = gi0 * invl + b_gru_ih[t]       + wo[t];
    gi1 = gi1 * invl + b_gru_ih[t + 256] + wo[t + 256];
    gi2 = gi2 * invl + b_gru_ih[t + 512] + wo[t + 512];
    gh0 += b_gru_hh[t]; gh1 += b_gru_hh[t + 256]; gh2 += b_gru_hh[t + 512];
    const float h_old = h[b * H_ + t];
    const float r = fast_sigmoid(gi0 + gh0);
    const float z = fast_sigmoid(gi1 + gh1);
    const float nn = fast_tanh(gi2 + r * gh2);
    const float hnew = (1.0f - z) * nn + z * h_old;
    h[b * H_ + t] = hnew;               // consumed next launch: plain OK
    shn[t] = hnew;
    __syncthreads();

    {
      float a1 = b_s1[t], a2 = b_h2h[t];
      const float* w1 = Wt_s1 + t;
      const float* w2 = Wt_h2h + t;
#pragma unroll 8
      for (int c = 0; c < H_; ++c) {
        float vv = shn[c];
        a1 += w1[(size_t)c * H_] * vv;
        a2 += w2[(size_t)c * H_] * vv;
      }
      ss1[t] = a1;
      pp[b * H_ + t] = a2;              // consumed next launch: plain OK
    }
    __syncthreads();

    const int wv = t >> 6, lane = t & 63;
    for (int vv = wv; vv < V_; vv += 4) {
      float4 wr = *(const float4*)&w_s2[(size_t)vv * H_ + lane * 4];
      float4 sv = *(const float4*)&ss1[lane * 4];
      float acc = wr.x * sv.x + wr.y * sv.y + wr.z * sv.z + wr.w * sv.w;
#pragma unroll
      for (int off = 32; off > 0; off >>= 1) acc += __shfl_xor(acc, off);
      if (lane == 0) sst[vv] = acc + b_s2[vv];
    }
    __syncthreads();

    if (t < 64) {
      float val = (lane < V_) ? sst[lane] : -INFINITY;
      float m = val;
#pragma unroll
      for (int off = 32; off > 0; off >>= 1) m = fmaxf(m, __shfl_xor(m, off));
      unsigned long long msk = __ballot(val == m);
      int amax = __ffsll(msk) - 1;   // first index achieving max (matches jnp.argmax)
      float e = (lane < V_) ? __expf(val - m) : 0.0f;
      float ssum = e;
#pragma unroll
      for (int off = 32; off > 0; off >>= 1) ssum += __shfl_xor(ssum, off);
      if (lane < V_) out[((size_t)b * T_ + tstep) * V_ + lane] = e / ssum;
      if (lane == 0) pre[b] = amax;
    }
  }
}

extern "C" void kernel_launch(void* const* d_in, const int* in_sizes, int n_in,
                              void* d_out, int out_size, void* d_ws, size_t ws_size,
                              hipStream_t stream) {
  (void)in_sizes; (void)n_in; (void)out_size; (void)ws_size;
  const float* feat     = (const float*)d_in[0];
  const float* w_i2h    = (const float*)d_in[1];
  const float* w_h2h    = (const float*)d_in[2];
  const float* b_h2h    = (const float*)d_in[3];
  const float* w_score  = (const float*)d_in[4];
  const float* w_gru_ih = (const float*)d_in[5];
  const float* w_gru_hh = (const float*)d_in[6];
  const float* b_gru_ih = (const float*)d_in[7];
  const float* b_gru_hh = (const float*)d_in[8];
  const float* w_s1     = (const float*)d_in[9];
  const float* b_s1     = (const float*)d_in[10];
  const float* w_s2     = (const float*)d_in[11];
  const float* b_s2     = (const float*)d_in[12];
  float* out = (float*)d_out;

  char* ws = (char*)d_ws;
  size_t off = 0;
  auto alloc = [&](size_t bytes) { void* p = ws + off; off += (bytes + 255) & ~(size_t)255; return p; };
  _Float16* fph   = (_Float16*)alloc((size_t)B_ * N_ * H_ * 2);      // 16.8 MB fp16
  _Float16* feath = (_Float16*)alloc((size_t)B_ * N_ * C_ * 2);      // 33.6 MB fp16
  float* part_ctx = (float*)alloc((size_t)B_ * CHUNKS_ * C_ * 4);    // 2 MB (plain stores)
  float* part_l   = (float*)alloc((size_t)B_ * CHUNKS_ * 4);
  float* ctx_raw  = (float*)alloc((size_t)B_ * C_ * 4);
  float* l_total  = (float*)alloc((size_t)B_ * 4);
  float* pgi      = (float*)alloc((size_t)4 * B_ * G3_ * 4);
  float* pgh      = (float*)alloc((size_t)4 * B_ * G3_ * 4);
  float* WtA      = (float*)alloc((size_t)C_ * G3_ * 4);             // [c][j]
  float* WtO      = (float*)alloc((size_t)V_ * G3_ * 4);             // [v][j]
  float* WtH      = (float*)alloc((size_t)H_ * G3_ * 4);             // [c][j]
  float* Wt_s1    = (float*)alloc((size_t)H_ * H_ * 4);
  float* Wt_h2h   = (float*)alloc((size_t)H_ * H_ * 4);
  float* h        = (float*)alloc((size_t)B_ * H_ * 4);
  float* pp       = (float*)alloc((size_t)B_ * H_ * 4);
  int*   pre      = (int*)alloc((size_t)B_ * 4);
  int*   cnt      = (int*)alloc((size_t)T_ * 16 * 4);

  init_kernel<<<(T_ * 16 + 255) / 256, 256, 0, stream>>>(b_h2h, h, pp, pre, cnt);
  fp_gemm<<<dim3((B_ * N_) / 64, H_ / 64), 256, 0, stream>>>(feat, w_i2h, fph);
  feat_to_fp16<<<(B_ * N_ * C_ / 4 + 255) / 256, 256, 0, stream>>>(feat, feath, B_ * N_ * C_ / 4);
  transpose_split<<<(G3_ * CV_ + 255) / 256, 256, 0, stream>>>(w_gru_ih, WtA, WtO, G3_, CV_, C_);
  transpose_split<<<(G3_ * H_ + 255) / 256, 256, 0, stream>>>(w_gru_hh, WtH, WtH, G3_, H_, H_);
  transpose_split<<<(H_ * H_ + 255) / 256, 256, 0, stream>>>(w_s1, Wt_s1, Wt_s1, H_, H_, H_);
  transpose_split<<<(H_ * H_ + 255) / 256, 256, 0, stream>>>(w_h2h, Wt_h2h, Wt_h2h, H_, H_, H_);

  for (int tstep = 0; tstep < T_; ++tstep) {
    k1_attn<<<B_ * CHUNKS_, 256, 0, stream>>>(feath, fph, w_score, pp, part_ctx, part_l);
    ktail<<<48, 256, 0, stream>>>(tstep, part_ctx, part_l, ctx_raw, l_total, h,
                                  WtA, WtH, pgi, pgh, WtO,
                                  b_gru_ih, b_gru_hh, Wt_s1, b_s1, Wt_h2h, b_h2h,
                                  w_s2, b_s2, pp, pre, cnt, out);
  }
}

// Round 21
// 15422.324 us; speedup vs baseline: 1.3095x; 1.3095x over previous
//
#include <hip/hip_runtime.h>
#include <math.h>

#define B_ 32
#define N_ 1024
#define C_ 512
#define H_ 256
#define V_ 50
#define T_ 501
#define CV_ 562     // C + V
#define G3_ 768     // 3*H
#define CHUNKS_ 32  // K1 blocks per batch row
#define POSB_ 32    // positions per K1 block

typedef float    f32x4 __attribute__((ext_vector_type(4)));
typedef _Float16 f16x4 __attribute__((ext_vector_type(4)));
typedef _Float16 f16x8 __attribute__((ext_vector_type(8)));

__device__ __forceinline__ float fast_rcp(float x) { return __builtin_amdgcn_rcpf(x); }
__device__ __forceinline__ float fast_tanh(float x) {
  float e = __expf(2.0f * x);
  return 1.0f - 2.0f * fast_rcp(e + 1.0f);
}
__device__ __forceinline__ float fast_sigmoid(float x) {
  return fast_rcp(1.0f + __expf(-x));
}

// ---------------- feat_proj GEMM: FPh[m][h] = fp16( sum_c A[m][c] * W[h][c] ) ----------------
__global__ __launch_bounds__(256) void fp_gemm(const float* __restrict__ A,
                                               const float* __restrict__ W,
                                               _Float16* __restrict__ FPh) {
  __shared__ __align__(16) float As[16][68];
  __shared__ __align__(16) float Ws[16][68];
  const int t = threadIdx.x;
  const int m0 = blockIdx.x * 64;
  const int h0 = blockIdx.y * 64;
  const int lr = t & 63;
  const int kg = t >> 6;
  const int tx = t & 15, ty = t >> 4;
  float acc[4][4] = {};
  for (int k0 = 0; k0 < C_; k0 += 16) {
    float4 av = *(const float4*)&A[(size_t)(m0 + lr) * C_ + k0 + kg * 4];
    float4 wv = *(const float4*)&W[(size_t)(h0 + lr) * C_ + k0 + kg * 4];
    As[kg*4+0][lr] = av.x; As[kg*4+1][lr] = av.y; As[kg*4+2][lr] = av.z; As[kg*4+3][lr] = av.w;
    Ws[kg*4+0][lr] = wv.x; Ws[kg*4+1][lr] = wv.y; Ws[kg*4+2][lr] = wv.z; Ws[kg*4+3][lr] = wv.w;
    __syncthreads();
#pragma unroll
    for (int kk = 0; kk < 16; ++kk) {
      float4 a = *(const float4*)&As[kk][ty * 4];
      float4 w = *(const float4*)&Ws[kk][tx * 4];
      acc[0][0] += a.x*w.x; acc[0][1] += a.x*w.y; acc[0][2] += a.x*w.z; acc[0][3] += a.x*w.w;
      acc[1][0] += a.y*w.x; acc[1][1] += a.y*w.y; acc[1][2] += a.y*w.z; acc[1][3] += a.y*w.w;
      acc[2][0] += a.z*w.x; acc[2][1] += a.z*w.y; acc[2][2] += a.z*w.z; acc[2][3] += a.z*w.w;
      acc[3][0] += a.w*w.x; acc[3][1] += a.w*w.y; acc[3][2] += a.w*w.z; acc[3][3] += a.w*w.w;
    }
    __syncthreads();
  }
#pragma unroll
  for (int i = 0; i < 4; ++i) {
    f16x4 o;
    o.x = (_Float16)acc[i][0]; o.y = (_Float16)acc[i][1];
    o.z = (_Float16)acc[i][2]; o.w = (_Float16)acc[i][3];
    *(f16x4*)&FPh[(size_t)(m0 + ty*4 + i) * H_ + h0 + tx*4] = o;
  }
}

// ---------------- feat -> fp16 (one-time) ----------------
__global__ void feat_to_fp16(const float* __restrict__ src, _Float16* __restrict__ dst,
                             int total4) {
  int i = blockIdx.x * 256 + threadIdx.x;
  if (i >= total4) return;
  f32x4 v = *(const f32x4*)&src[(size_t)i * 4];
  f16x4 o; o.x = (_Float16)v.x; o.y = (_Float16)v.y; o.z = (_Float16)v.z; o.w = (_Float16)v.w;
  *(f16x4*)&dst[(size_t)i * 4] = o;
}

// ---------------- weight transpose (one-time): dstA[c][j] = src[j][c] for c<splitc, rest -> dstB ----------------
__global__ void transpose_split(const float* __restrict__ src, float* __restrict__ dstA,
                                float* __restrict__ dstB, int rows, int cols, int splitc) {
  int i = blockIdx.x * 256 + threadIdx.x;
  if (i >= rows * cols) return;
  int j = i / cols, c = i - j * cols;
  float v = src[i];
  if (c < splitc) dstA[(size_t)c * rows + j] = v;
  else            dstB[(size_t)(c - splitc) * rows + j] = v;
}

// ---------------- init: h=0, pp=b_h2h, pre=0 ----------------
__global__ void init_kernel(const float* __restrict__ b_h2h, float* __restrict__ h,
                            float* __restrict__ pp, int* __restrict__ pre) {
  int i = blockIdx.x * blockDim.x + threadIdx.x;
  if (i < B_ * H_) { h[i] = 0.0f; pp[i] = b_h2h[i & (H_ - 1)]; }
  if (i < B_) pre[i] = 0;
}

// ---------------- K1: attention scores -> exp -> partial ctx -> PLAIN per-block stores ----------------
// grid = B*CHUNKS blocks, block = 256 (4 waves, 8 positions each). Full preload: 16 NT loads in
// flight per wave (384 B/lane) to cover ~900cy HBM latency; compute consumes them in order.
__global__ __launch_bounds__(256) void k1_attn(
    const _Float16* __restrict__ feath, const _Float16* __restrict__ fph,
    const float* __restrict__ w_score, const float* __restrict__ pp,
    float* __restrict__ part_ctx, float* __restrict__ part_l) {
  __shared__ __align__(16) float lds_ctx[4 * C_];
  __shared__ float lds_l[4];

  const int t = threadIdx.x;
  const int wv = t >> 6;
  const int lane = t & 63;
  const int b = blockIdx.x >> 5;        // / CHUNKS_
  const int chunk = blockIdx.x & (CHUNKS_ - 1);

  float4 ppr = *(const float4*)&pp[b * H_ + lane * 4];
  float4 wsr = *(const float4*)&w_score[lane * 4];
  const int n0 = chunk * POSB_ + wv * 8;
  const _Float16* fp0 = fph + (size_t)b * N_ * H_ + (size_t)n0 * H_ + lane * 4;
  const _Float16* ft0 = feath + (size_t)b * N_ * C_ + (size_t)n0 * C_ + lane * 8;

  // ---- preload all 8 iterations' operands: 16 independent NT loads ----
  f16x4 v[8];
  f16x8 f[8];
#pragma unroll
  for (int i = 0; i < 8; ++i) {
    v[i] = __builtin_nontemporal_load((const f16x4*)(fp0 + (size_t)i * H_));
    f[i] = __builtin_nontemporal_load((const f16x8*)(ft0 + (size_t)i * C_));
  }

  float aA0 = 0.f, aA1 = 0.f, aA2 = 0.f, aA3 = 0.f;
  float aB0 = 0.f, aB1 = 0.f, aB2 = 0.f, aB3 = 0.f;
  float lacc = 0.f;
#pragma unroll
  for (int i = 0; i < 8; ++i) {
    float s = fast_tanh((float)v[i].x + ppr.x) * wsr.x + fast_tanh((float)v[i].y + ppr.y) * wsr.y
            + fast_tanh((float)v[i].z + ppr.z) * wsr.z + fast_tanh((float)v[i].w + ppr.w) * wsr.w;
#pragma unroll
    for (int off = 32; off > 0; off >>= 1) s += __shfl_xor(s, off);
    float p = __expf(s);   // |s| <= sum|w_score| ~ 10 -> safe without max-subtraction
    lacc += p;
    aA0 += p * (float)f[i].s0; aA1 += p * (float)f[i].s1; aA2 += p * (float)f[i].s2; aA3 += p * (float)f[i].s3;
    aB0 += p * (float)f[i].s4; aB1 += p * (float)f[i].s5; aB2 += p * (float)f[i].s6; aB3 += p * (float)f[i].s7;
  }
  {
    float4 o0; o0.x = aA0; o0.y = aA1; o0.z = aA2; o0.w = aA3;
    float4 o1; o1.x = aB0; o1.y = aB1; o1.z = aB2; o1.w = aB3;
    *(float4*)&lds_ctx[wv * C_ + lane * 8] = o0;
    *(float4*)&lds_ctx[wv * C_ + lane * 8 + 4] = o1;
  }
  if (lane == 0) lds_l[wv] = lacc;
  __syncthreads();
  {
    float c0 = lds_ctx[t] + lds_ctx[C_ + t] + lds_ctx[2 * C_ + t] + lds_ctx[3 * C_ + t];
    float c1 = lds_ctx[t + 256] + lds_ctx[C_ + t + 256] + lds_ctx[2 * C_ + t + 256] + lds_ctx[3 * C_ + t + 256];
    float* pc = &part_ctx[((size_t)b * CHUNKS_ + chunk) * C_];
    pc[t] = c0;                 // plain stores, distinct addresses: zero contention
    pc[t + 256] = c1;
    if (t == 0) part_l[b * CHUNKS_ + chunk] = lds_l[0] + lds_l[1] + lds_l[2] + lds_l[3];
  }
}

// ---------------- K1.5: reduce 32 chunks ONCE -> ctx_raw[b][c], l_total[b] ----------------
// grid = 32 blocks (one per b), 512 threads (one per c). Coalesced: consecutive t = consecutive addr.
__global__ __launch_bounds__(512) void kred(
    const float* __restrict__ part_ctx, const float* __restrict__ part_l,
    float* __restrict__ ctx_raw, float* __restrict__ l_total) {
  const int b = blockIdx.x;
  const int t = threadIdx.x;
  const float* src = part_ctx + (size_t)b * CHUNKS_ * C_ + t;
  float s = 0.f;
#pragma unroll 8
  for (int ch = 0; ch < CHUNKS_; ++ch) s += src[(size_t)ch * C_];
  ctx_raw[b * C_ + t] = s;
  if (t < 64) {
    float lv = (t < CHUNKS_) ? part_l[b * CHUNKS_ + t] : 0.0f;
#pragma unroll
    for (int off = 32; off > 0; off >>= 1) lv += __shfl_xor(lv, off);
    if (t == 0) l_total[b] = lv;
  }
}

// ---------------- K2a: gate GEMM (weights read ONCE per step) ----------------
// grid = dim3(12 j-tiles, 4 k-splits), block = 256
__global__ __launch_bounds__(256) void k2a_gates(
    const float* __restrict__ ctx_raw, const float* __restrict__ h,
    const float* __restrict__ WtA, const float* __restrict__ WtH,
    float* __restrict__ pgi, float* __restrict__ pgh) {
  __shared__ __align__(16) float wlds[64][64];   // [k][j]
  __shared__ __align__(16) float clds[32][64];   // [b][k]
  const int t = threadIdx.x;
  const int j0 = blockIdx.x * 64;
  const int ks = blockIdx.y;
  const int jl = (t & 31) * 2;        // 2 j's per thread
  const int b0 = (t >> 5) * 4;        // 4 b's per thread

  float acc[2][4] = {};
  // ---- gi: k in [ks*128, ks*128+128), two 64-tiles ----
#pragma unroll
  for (int kt = 0; kt < 2; ++kt) {
    const int k0 = ks * 128 + kt * 64;
    __syncthreads();
#pragma unroll
    for (int q = 0; q < 4; ++q) {        // stage W slice: 64 rows x 16 float4
      int idx = q * 256 + t; int r = idx >> 4, f4 = (idx & 15) * 4;
      *(float4*)&wlds[r][f4] = *(const float4*)&WtA[(size_t)(k0 + r) * G3_ + j0 + f4];
    }
#pragma unroll
    for (int q = 0; q < 2; ++q) {        // stage ctx slice: 32 rows x 16 float4
      int idx = q * 256 + t; int bb = idx >> 4, f4 = (idx & 15) * 4;
      *(float4*)&clds[bb][f4] = *(const float4*)&ctx_raw[(size_t)bb * C_ + k0 + f4];
    }
    __syncthreads();
#pragma unroll 8
    for (int k = 0; k < 64; ++k) {
      float w0 = wlds[k][jl], w1 = wlds[k][jl + 1];
      float x0 = clds[b0][k], x1 = clds[b0 + 1][k], x2 = clds[b0 + 2][k], x3 = clds[b0 + 3][k];
      acc[0][0] += w0 * x0; acc[0][1] += w0 * x1; acc[0][2] += w0 * x2; acc[0][3] += w0 * x3;
      acc[1][0] += w1 * x0; acc[1][1] += w1 * x1; acc[1][2] += w1 * x2; acc[1][3] += w1 * x3;
    }
  }
#pragma unroll
  for (int i = 0; i < 2; ++i)
#pragma unroll
    for (int q = 0; q < 4; ++q)
      pgi[((size_t)ks * B_ + b0 + q) * G3_ + j0 + jl + i] = acc[i][q];

  // ---- gh: k in [ks*64, ks*64+64), one tile ----
  float acb[2][4] = {};
  {
    const int k0 = ks * 64;
    __syncthreads();
#pragma unroll
    for (int q = 0; q < 4; ++q) {        // 64 rows x 16 float4
      int idx = q * 256 + t; int r = idx >> 4, f4 = (idx & 15) * 4;
      *(float4*)&wlds[r][f4] = *(const float4*)&WtH[(size_t)(k0 + r) * G3_ + j0 + f4];
    }
#pragma unroll
    for (int q = 0; q < 2; ++q) {        // 32 rows x 16 float4
      int idx = q * 256 + t; int bb = idx >> 4, f4 = (idx & 15) * 4;
      *(float4*)&clds[bb][f4] = *(const float4*)&h[(size_t)bb * H_ + k0 + f4];
    }
    __syncthreads();
#pragma unroll 8
    for (int k = 0; k < 64; ++k) {
      float w0 = wlds[k][jl], w1 = wlds[k][jl + 1];
      float x0 = clds[b0][k], x1 = clds[b0 + 1][k], x2 = clds[b0 + 2][k], x3 = clds[b0 + 3][k];
      acb[0][0] += w0 * x0; acb[0][1] += w0 * x1; acb[0][2] += w0 * x2; acb[0][3] += w0 * x3;
      acb[1][0] += w1 * x0; acb[1][1] += w1 * x1; acb[1][2] += w1 * x2; acb[1][3] += w1 * x3;
    }
  }
#pragma unroll
  for (int i = 0; i < 2; ++i)
#pragma unroll
    for (int q = 0; q < 4; ++q)
      pgh[((size_t)ks * B_ + b0 + q) * G3_ + j0 + jl + i] = acb[i][q];
}

// ---------------- K2b: per-b tail. grid = 32, block = 512 ----------------
__global__ __launch_bounds__(512) void k2b_tail(
    int tstep,
    const float* __restrict__ pgi, const float* __restrict__ pgh,
    const float* __restrict__ l_total,
    const float* __restrict__ WtO,
    const float* __restrict__ b_gru_ih, const float* __restrict__ b_gru_hh,
    const float* __restrict__ Wt_s1, const float* __restrict__ b_s1,
    const float* __restrict__ Wt_h2h, const float* __restrict__ b_h2h,
    const float* __restrict__ w_s2, const float* __restrict__ b_s2,
    float* __restrict__ h, float* __restrict__ pp, int* __restrict__ pre,
    float* __restrict__ out) {
  __shared__ __align__(16) float shn[H_];
  __shared__ __align__(16) float ss1[H_];
  __shared__ float sst[64];
  const int b = blockIdx.x;
  const int t = threadIdx.x;
  const int prev = pre[b];
  const float invl = 1.0f / l_total[b];

  if (t < H_) {
    float gi0 = 0.f, gi1 = 0.f, gi2 = 0.f, gh0 = 0.f, gh1 = 0.f, gh2 = 0.f;
#pragma unroll
    for (int ks = 0; ks < 4; ++ks) {
      const float* pg = pgi + ((size_t)ks * B_ + b) * G3_;
      const float* ph = pgh + ((size_t)ks * B_ + b) * G3_;
      gi0 += pg[t]; gi1 += pg[t + 256]; gi2 += pg[t + 512];
      gh0 += ph[t]; gh1 += ph[t + 256]; gh2 += ph[t + 512];
    }
    const float* wo = WtO + (size_t)prev * G3_;
    gi0 = gi0 * invl + b_gru_ih[t]       + wo[t];
    gi1 = gi1 * invl + b_gru_ih[t + 256] + wo[t + 256];
    gi2 = gi2 * invl + b_gru_ih[t + 512] + wo[t + 512];
    gh0 += b_gru_hh[t]; gh1 += b_gru_hh[t + 256]; gh2 += b_gru_hh[t + 512];
    const float h_old = h[b * H_ + t];
    const float r = fast_sigmoid(gi0 + gh0);
    const float z = fast_sigmoid(gi1 + gh1);
    const float nn = fast_tanh(gi2 + r * gh2);
    const float hnew = (1.0f - z) * nn + z * h_old;
    h[b * H_ + t] = hnew;
    shn[t] = hnew;
  }
  __syncthreads();

  if (t < H_) {
    float acc = b_s1[t];
    const float* w1 = Wt_s1 + t;
#pragma unroll 8
    for (int c = 0; c < H_; ++c) acc += w1[(size_t)c * H_] * shn[c];
    ss1[t] = acc;
  } else if (t < 2 * H_) {
    const int tt = t - H_;
    float acc = b_h2h[tt];
    const float* wh2 = Wt_h2h + tt;
#pragma unroll 8
    for (int c = 0; c < H_; ++c) acc += wh2[(size_t)c * H_] * shn[c];
    pp[b * H_ + tt] = acc;
  }
  __syncthreads();

  const int wv = t >> 6, lane = t & 63;
  for (int v = wv; v < V_; v += 8) {
    float4 wr = *(const float4*)&w_s2[(size_t)v * H_ + lane * 4];
    float4 sv = *(const float4*)&ss1[lane * 4];
    float acc = wr.x * sv.x + wr.y * sv.y + wr.z * sv.z + wr.w * sv.w;
#pragma unroll
    for (int off = 32; off > 0; off >>= 1) acc += __shfl_xor(acc, off);
    if (lane == 0) sst[v] = acc + b_s2[v];
  }
  __syncthreads();

  if (t < 64) {
    float val = (lane < V_) ? sst[lane] : -INFINITY;
    float m = val;
#pragma unroll
    for (int off = 32; off > 0; off >>= 1) m = fmaxf(m, __shfl_xor(m, off));
    unsigned long long msk = __ballot(val == m);
    int amax = __ffsll(msk) - 1;   // first index achieving max (matches jnp.argmax)
    float e = (lane < V_) ? __expf(val - m) : 0.0f;
    float ssum = e;
#pragma unroll
    for (int off = 32; off > 0; off >>= 1) ssum += __shfl_xor(ssum, off);
    if (lane < V_) out[((size_t)b * T_ + tstep) * V_ + lane] = e / ssum;
    if (lane == 0) pre[b] = amax;
  }
}

extern "C" void kernel_launch(void* const* d_in, const int* in_sizes, int n_in,
                              void* d_out, int out_size, void* d_ws, size_t ws_size,
                              hipStream_t stream) {
  (void)in_sizes; (void)n_in; (void)out_size; (void)ws_size;
  const float* feat     = (const float*)d_in[0];
  const float* w_i2h    = (const float*)d_in[1];
  const float* w_h2h    = (const float*)d_in[2];
  const float* b_h2h    = (const float*)d_in[3];
  const float* w_score  = (const float*)d_in[4];
  const float* w_gru_ih = (const float*)d_in[5];
  const float* w_gru_hh = (const float*)d_in[6];
  const float* b_gru_ih = (const float*)d_in[7];
  const float* b_gru_hh = (const float*)d_in[8];
  const float* w_s1     = (const float*)d_in[9];
  const float* b_s1     = (const float*)d_in[10];
  const float* w_s2     = (const float*)d_in[11];
  const float* b_s2     = (const float*)d_in[12];
  float* out = (float*)d_out;

  char* ws = (char*)d_ws;
  size_t off = 0;
  auto alloc = [&](size_t bytes) { void* p = ws + off; off += (bytes + 255) & ~(size_t)255; return p; };
  _Float16* fph   = (_Float16*)alloc((size_t)B_ * N_ * H_ * 2);      // 16.8 MB fp16
  _Float16* feath = (_Float16*)alloc((size_t)B_ * N_ * C_ * 2);      // 33.6 MB fp16
  float* part_ctx = (float*)alloc((size_t)B_ * CHUNKS_ * C_ * 4);    // 2 MB (plain stores)
  float* part_l   = (float*)alloc((size_t)B_ * CHUNKS_ * 4);
  float* ctx_raw  = (float*)alloc((size_t)B_ * C_ * 4);
  float* l_total  = (float*)alloc((size_t)B_ * 4);
  float* pgi      = (float*)alloc((size_t)4 * B_ * G3_ * 4);
  float* pgh      = (float*)alloc((size_t)4 * B_ * G3_ * 4);
  float* WtA      = (float*)alloc((size_t)C_ * G3_ * 4);             // [c][j]
  float* WtO      = (float*)alloc((size_t)V_ * G3_ * 4);             // [v][j]
  float* WtH      = (float*)alloc((size_t)H_ * G3_ * 4);             // [c][j]
  float* Wt_s1    = (float*)alloc((size_t)H_ * H_ * 4);
  float* Wt_h2h   = (float*)alloc((size_t)H_ * H_ * 4);
  float* h        = (float*)alloc((size_t)B_ * H_ * 4);
  float* pp       = (float*)alloc((size_t)B_ * H_ * 4);
  int*   pre      = (int*)alloc((size_t)B_ * 4);

  init_kernel<<<32, 256, 0, stream>>>(b_h2h, h, pp, pre);
  fp_gemm<<<dim3((B_ * N_) / 64, H_ / 64), 256, 0, stream>>>(feat, w_i2h, fph);
  feat_to_fp16<<<(B_ * N_ * C_ / 4 + 255) / 256, 256, 0, stream>>>(feat, feath, B_ * N_ * C_ / 4);
  transpose_split<<<(G3_ * CV_ + 255) / 256, 256, 0, stream>>>(w_gru_ih, WtA, WtO, G3_, CV_, C_);
  transpose_split<<<(G3_ * H_ + 255) / 256, 256, 0, stream>>>(w_gru_hh, WtH, WtH, G3_, H_, H_);
  transpose_split<<<(H_ * H_ + 255) / 256, 256, 0, stream>>>(w_s1, Wt_s1, Wt_s1, H_, H_, H_);
  transpose_split<<<(H_ * H_ + 255) / 256, 256, 0, stream>>>(w_h2h, Wt_h2h, Wt_h2h, H_, H_, H_);

  for (int tstep = 0; tstep < T_; ++tstep) {
    k1_attn<<<B_ * CHUNKS_, 256, 0, stream>>>(feath, fph, w_score, pp, part_ctx, part_l);
    kred<<<B_, 512, 0, stream>>>(part_ctx, part_l, ctx_raw, l_total);
    k2a_gates<<<dim3(12, 4), 256, 0, stream>>>(ctx_raw, h, WtA, WtH, pgi, pgh);
    k2b_tail<<<B_, 512, 0, stream>>>(tstep, pgi, pgh, l_total, WtO,
                                     b_gru_ih, b_gru_hh, Wt_s1, b_s1, Wt_h2h, b_h2h,
                                     w_s2, b_s2, h, pp, pre, out);
  }
}